// Round 26
// baseline (476.258 us; speedup 1.0000x reference)
//
#include <hip/hip_runtime.h>

// LinearShift: out = round_to_fixed(x) @ v.T + round_to_fixed(bias)
// ROUND 26: B bypasses LDS (global->VGPR fragment loads). Diagnosis: LDS
// traffic/tile was 160KB (96 read + 64 gload_lds WRITE) ~ 2000 cyc at 85B/c
// -- THE plateau (2430 cyc/tile, MfmaUtil 46% = MFMA hidden under LDS).
// B-frag global reads are 64B-line-perfect (lane=fr+16*kb reads bytes
// kb*16..+16 of row fr: 16 full lines/wave) and B (33MB) is L2/L3-resident.
// A-only LDS: 80KB/tile ~ 1000 cyc -> floor max(MFMA 1242, LDS 1000).
// Ledger: 4 slots x 16KB A, lookahead-2; per tile issue B4(T+1) then
// A2(T+2); gate VM2 retires {A2(T+1),B4(T+1)} leaves A2(T+2); tail NT-2
// VM0, NT-1 none. bf16 path validated r25 (absmax 0.25 < 1.11).

typedef short short8 __attribute__((ext_vector_type(8)));   // 8 bf16
typedef unsigned short ushort4v __attribute__((ext_vector_type(4)));
typedef float floatx4 __attribute__((ext_vector_type(4)));

__device__ __forceinline__ float qfix(float x) {
    float r = floorf(x * 256.0f + 0.5f);
    r = fminf(fmaxf(r, -32768.0f), 32767.0f);
    return r * 0.00390625f;
}

// float -> bf16 bits, round-nearest-even (inputs finite).
__device__ __forceinline__ unsigned short f2bf(float f) {
    unsigned int b = __builtin_bit_cast(unsigned int, f);
    b += 0x7FFFu + ((b >> 16) & 1u);
    return (unsigned short)(b >> 16);
}

__global__ __launch_bounds__(256) void quantize_x_kernel(
        const float* __restrict__ x, unsigned short* __restrict__ xq, int n4) {
    int i = blockIdx.x * 256 + threadIdx.x;
    const int stride = gridDim.x * 256;
    for (; i < n4; i += stride) {
        float4 v = reinterpret_cast<const float4*>(x)[i];
        ushort4v o;
        o[0] = f2bf(qfix(v.x));
        o[1] = f2bf(qfix(v.y));
        o[2] = f2bf(qfix(v.z));
        o[3] = f2bf(qfix(v.w));
        reinterpret_cast<ushort4v*>(xq)[i] = o;
    }
}

__global__ __launch_bounds__(256) void make_v_kernel(
        const float* __restrict__ shift, const float* __restrict__ sign,
        unsigned short* __restrict__ v, int n4) {
    int i = blockIdx.x * 256 + threadIdx.x;
    const int stride = gridDim.x * 256;
    for (; i < n4; i += stride) {
        float4 sh = reinterpret_cast<const float4*>(shift)[i];
        float4 sg = reinterpret_cast<const float4*>(sign)[i];
        ushort4v o;
        o[0] = f2bf(ldexpf((rintf(sg.x) == 0.0f) ? 1.0f : -1.0f, (int)rintf(sh.x)));
        o[1] = f2bf(ldexpf((rintf(sg.y) == 0.0f) ? 1.0f : -1.0f, (int)rintf(sh.y)));
        o[2] = f2bf(ldexpf((rintf(sg.z) == 0.0f) ? 1.0f : -1.0f, (int)rintf(sh.z)));
        o[3] = f2bf(ldexpf((rintf(sg.w) == 0.0f) ? 1.0f : -1.0f, (int)rintf(sh.w)));
        reinterpret_cast<ushort4v*>(v)[i] = o;
    }
}

__device__ __forceinline__ void async_load16(const void* g, void* l) {
    __builtin_amdgcn_global_load_lds(
        (const __attribute__((address_space(1))) unsigned int*)g,
        (__attribute__((address_space(3))) unsigned int*)l,
        16, 0, 0);
}

// A staging (r15-validated): LDS[r][b] = A[row0+r][k0 + (b^((r>>1)&3))*8].
// One K-tile of A = 256x32 bf16 = 16KB = 2 loads/thread.
#define STAGE_A(NS)  do {                                                 \
    async_load16(pA0, (NS) + t * 8);                                      \
    async_load16(pA1, (NS) + 4096 + t * 8);                               \
    pA0 += 32; pA1 += 32; } while (0)

#define FENCE() asm volatile("" ::: "memory")
#define VM2()  do { FENCE(); __builtin_amdgcn_s_waitcnt(0x0F72); FENCE(); } while (0)
#define VM0()  do { FENCE(); __builtin_amdgcn_s_waitcnt(0x0F70); FENCE(); } while (0)
#define BAR()  do { FENCE(); __builtin_amdgcn_s_barrier(); FENCE(); } while (0)

// LDS (dynamic, 64KB): 4 slots x A[256][32] bf16 (16KB = 8192 els/slot).
// Rows 0-127 in first 8KB of slot, rows 128-255 in second 8KB.
__global__ __launch_bounds__(512, 2) void gemm8_kernel(
        const unsigned short* __restrict__ A,   // M x K (bf16 bits)
        const unsigned short* __restrict__ B,   // N x K (bf16 bits)
        const float* __restrict__ bias,         // N
        float* __restrict__ C,                  // M x N
        int M, int N, int K) {
    extern __shared__ unsigned short smem[];
    const int t = threadIdx.x;
    const int lane = t & 63;
    const int w = t >> 6;
    const int wrow = w >> 2;   // 0..1
    const int wcol = w & 3;    // 0..3
    const int fr  = lane & 15;
    const int kb  = lane >> 4; // 0..3

    // T1: bijective XCD swizzle (nwg = 512, % 8 == 0)
    const int nwg = gridDim.x;
    const int bid = blockIdx.x;
    const int cpx = nwg >> 3;
    const int swz = (bid & 7) * cpx + (bid >> 3);
    const int ntN = N >> 8;
    const int bm = (swz / ntN) << 8;
    const int bn = (swz % ntN) << 8;

    // A stage pointers (r15-validated), +32 els/tile.
    const int r0  = t >> 2;
    const int cbo = ((t & 3) ^ ((t >> 3) & 3)) * 8;
    const unsigned short* pA0 = A + (size_t)(bm +       r0) * K + cbo;
    const unsigned short* pA1 = A + (size_t)(bm + 128 + r0) * K + cbo;

    // B fragment pointers (global->VGPR, L2-resident): per lane one b128
    // per (qn, nf). col = bn + qn*128 + wcol*32 + nf*16 + fr; +32 els/tile.
    const unsigned short* pB00 = B + (size_t)(bn +       wcol * 32 +      fr) * K + kb * 8;
    const unsigned short* pB01 = B + (size_t)(bn +       wcol * 32 + 16 + fr) * K + kb * 8;
    const unsigned short* pB10 = B + (size_t)(bn + 128 + wcol * 32 +      fr) * K + kb * 8;
    const unsigned short* pB11 = B + (size_t)(bn + 128 + wcol * 32 + 16 + fr) * K + kb * 8;

    // Swizzled A read base (bytes, slot 0): byte = row*64 + ((kb^((row>>1)&3))<<4).
    const int xk = ((kb ^ ((fr >> 1) & 3)) << 4);
    const char* sbase = (const char*)smem;
    const char* aRow = sbase + (wrow * 64 + fr) * 64 + xk;   // +sb +mf*1024 (+8192 for A1)

    // Prologue: stage A(0)->slot0, A(1)->slot1 (4 loads); load B(0) (4 loads);
    // drain; barrier.
    STAGE_A(smem);
    STAGE_A(smem + 8192);
    short8 bfA[2][2], bfB[2][2];
    bfA[0][0] = *reinterpret_cast<const short8*>(pB00);
    bfA[0][1] = *reinterpret_cast<const short8*>(pB01);
    bfA[1][0] = *reinterpret_cast<const short8*>(pB10);
    bfA[1][1] = *reinterpret_cast<const short8*>(pB11);
    pB00 += 32; pB01 += 32; pB10 += 32; pB11 += 32;
    VM0();
    BAR();

    floatx4 acc[2][2][4][2] = {};   // [qm][qn][mf][nf]
    const int NT = K >> 5;          // 128 (even)

    // Ledger: entering tile T, outstanding = A2(T+1) (left by prev VM2);
    // A(T) resident in slot T&3, B(T) in regs (retired by prev gate).
    // Body: read A-frags; load B4(T+1); stage A2(T+2) -> slot (T+2)&3
    // (= slot (T-2)&3, reads done 2 barriers ago: WAR safe); MFMA; gate
    // VM2 retires {A2(T+1), B4(T+1)}. Tail: T==NT-2 -> VM0; NT-1 -> none.
    auto body = [&](int T, short8 (&bfU)[2][2], short8 (&bfL)[2][2])
            __attribute__((always_inline)) {
        BAR();
        const int sb = (T & 3) << 14;

        short8 af0[4], af1[4];
        #pragma unroll
        for (int mf = 0; mf < 4; ++mf) {
            af0[mf] = *reinterpret_cast<const short8*>(aRow + sb +        mf * 1024);
            af1[mf] = *reinterpret_cast<const short8*>(aRow + sb + 8192 + mf * 1024);
        }

        if (T + 1 < NT) {
            bfL[0][0] = *reinterpret_cast<const short8*>(pB00);
            bfL[0][1] = *reinterpret_cast<const short8*>(pB01);
            bfL[1][0] = *reinterpret_cast<const short8*>(pB10);
            bfL[1][1] = *reinterpret_cast<const short8*>(pB11);
            pB00 += 32; pB01 += 32; pB10 += 32; pB11 += 32;
        }
        if (T + 2 < NT)
            STAGE_A(smem + ((T + 2) & 3) * 8192);

        #pragma unroll
        for (int mf = 0; mf < 4; ++mf)
          #pragma unroll
          for (int nf = 0; nf < 2; ++nf) {
            acc[0][0][mf][nf] = __builtin_amdgcn_mfma_f32_16x16x32_bf16(
                af0[mf], bfU[0][nf], acc[0][0][mf][nf], 0, 0, 0);
            acc[0][1][mf][nf] = __builtin_amdgcn_mfma_f32_16x16x32_bf16(
                af0[mf], bfU[1][nf], acc[0][1][mf][nf], 0, 0, 0);
            acc[1][1][mf][nf] = __builtin_amdgcn_mfma_f32_16x16x32_bf16(
                af1[mf], bfU[1][nf], acc[1][1][mf][nf], 0, 0, 0);
            acc[1][0][mf][nf] = __builtin_amdgcn_mfma_f32_16x16x32_bf16(
                af1[mf], bfU[0][nf], acc[1][0][mf][nf], 0, 0, 0);
          }

        if (T + 2 < NT)      { VM2(); }
        else if (T + 1 < NT) { VM0(); }
    };

    for (int T = 0; T < NT; T += 2) {
        body(T,     bfA, bfB);
        body(T + 1, bfB, bfA);
    }

    // Epilogue: C/D layout col=lane&15, row=(lane>>4)*4+reg (validated)
    #pragma unroll
    for (int qm = 0; qm < 2; ++qm)
      #pragma unroll
      for (int qn = 0; qn < 2; ++qn)
        #pragma unroll
        for (int nf = 0; nf < 2; ++nf) {
            const int gcol = bn + qn * 128 + wcol * 32 + nf * 16 + (lane & 15);
            const float bq = qfix(bias[gcol]);
            #pragma unroll
            for (int mf = 0; mf < 4; ++mf) {
                const int grow = bm + qm * 128 + wrow * 64 + mf * 16 + ((lane >> 4) << 2);
                float* p = C + (size_t)grow * N + gcol;
                #pragma unroll
                for (int r = 0; r < 4; ++r)
                    p[(size_t)r * N] = acc[qm][qn][mf][nf][r] + bq;
            }
        }
}

extern "C" void kernel_launch(void* const* d_in, const int* in_sizes, int n_in,
                              void* d_out, int out_size, void* d_ws, size_t ws_size,
                              hipStream_t stream) {
    const float* x     = (const float*)d_in[0];
    const float* shift = (const float*)d_in[1];
    const float* sign  = (const float*)d_in[2];
    const float* bias  = (const float*)d_in[3];
    float* out = (float*)d_out;

    const int N = in_sizes[3];            // 4096
    const int K = in_sizes[1] / N;        // 4096
    const int M = in_sizes[0] / K;        // 8192

    unsigned short* xq = (unsigned short*)d_ws;
    unsigned short* v  = xq + (size_t)M * K;

    quantize_x_kernel<<<2048, 256, 0, stream>>>(x, xq, M * K / 4);
    make_v_kernel<<<2048, 256, 0, stream>>>(shift, sign, v, N * K / 4);

    (void)hipFuncSetAttribute(reinterpret_cast<const void*>(gemm8_kernel),
                              hipFuncAttributeMaxDynamicSharedMemorySize, 65536);
    const int nblk = (M / 256) * (N / 256);   // 512
    gemm8_kernel<<<nblk, 512, 65536, stream>>>(xq, v, bias, out, M, N, K);
}

// Round 27
// 452.531 us; speedup vs baseline: 1.0524x; 1.0524x over previous
//
#include <hip/hip_runtime.h>

// LinearShift: out = round_to_fixed(x) @ v.T + round_to_fixed(bias)
// ROUND 27: B-bypass (global->VGPR) with DEPTH-2 prefetch. r26 failed on
// latency (MfmaUtil 25, VALUBusy 9, FETCH flat): VM2 gate waited on B(T+1)
// issued ~600cyc earlier -- L2/L3 latency on the critical path. Fix: load
// B(T+2) each tile (~1200cyc slack), triple-buffer B regs (static rotation,
// period 3). Ledger (FIFO): issue B4(T+2) then A2(T+2); gate VM6 retires
// {B4,A2}(T+1), leaves 6. Tail: NT-2 -> VM0; NT-1 -> none. LDS traffic
// 160->80KB/tile (A-only: 64KB read + 16KB write) -> floor ~max(MFMA 1242,
// LDS 1000) cyc/tile. B addressing validated r26 (absmax 0.25).

typedef short short8 __attribute__((ext_vector_type(8)));   // 8 bf16
typedef unsigned short ushort4v __attribute__((ext_vector_type(4)));
typedef float floatx4 __attribute__((ext_vector_type(4)));

__device__ __forceinline__ float qfix(float x) {
    float r = floorf(x * 256.0f + 0.5f);
    r = fminf(fmaxf(r, -32768.0f), 32767.0f);
    return r * 0.00390625f;
}

__device__ __forceinline__ unsigned short f2bf(float f) {
    unsigned int b = __builtin_bit_cast(unsigned int, f);
    b += 0x7FFFu + ((b >> 16) & 1u);
    return (unsigned short)(b >> 16);
}

__global__ __launch_bounds__(256) void quantize_x_kernel(
        const float* __restrict__ x, unsigned short* __restrict__ xq, int n4) {
    int i = blockIdx.x * 256 + threadIdx.x;
    const int stride = gridDim.x * 256;
    for (; i < n4; i += stride) {
        float4 v = reinterpret_cast<const float4*>(x)[i];
        ushort4v o;
        o[0] = f2bf(qfix(v.x));
        o[1] = f2bf(qfix(v.y));
        o[2] = f2bf(qfix(v.z));
        o[3] = f2bf(qfix(v.w));
        reinterpret_cast<ushort4v*>(xq)[i] = o;
    }
}

__global__ __launch_bounds__(256) void make_v_kernel(
        const float* __restrict__ shift, const float* __restrict__ sign,
        unsigned short* __restrict__ v, int n4) {
    int i = blockIdx.x * 256 + threadIdx.x;
    const int stride = gridDim.x * 256;
    for (; i < n4; i += stride) {
        float4 sh = reinterpret_cast<const float4*>(shift)[i];
        float4 sg = reinterpret_cast<const float4*>(sign)[i];
        ushort4v o;
        o[0] = f2bf(ldexpf((rintf(sg.x) == 0.0f) ? 1.0f : -1.0f, (int)rintf(sh.x)));
        o[1] = f2bf(ldexpf((rintf(sg.y) == 0.0f) ? 1.0f : -1.0f, (int)rintf(sh.y)));
        o[2] = f2bf(ldexpf((rintf(sg.z) == 0.0f) ? 1.0f : -1.0f, (int)rintf(sh.z)));
        o[3] = f2bf(ldexpf((rintf(sg.w) == 0.0f) ? 1.0f : -1.0f, (int)rintf(sh.w)));
        reinterpret_cast<ushort4v*>(v)[i] = o;
    }
}

__device__ __forceinline__ void async_load16(const void* g, void* l) {
    __builtin_amdgcn_global_load_lds(
        (const __attribute__((address_space(1))) unsigned int*)g,
        (__attribute__((address_space(3))) unsigned int*)l,
        16, 0, 0);
}

// A staging (r15-validated): LDS[r][b] = A[row0+r][k0 + (b^((r>>1)&3))*8].
#define STAGE_A(NS)  do {                                                 \
    async_load16(pA0, (NS) + t * 8);                                      \
    async_load16(pA1, (NS) + 4096 + t * 8);                               \
    pA0 += 32; pA1 += 32; } while (0)

#define LOAD_B(DST)  do {                                                 \
    DST[0][0] = *reinterpret_cast<const short8*>(pB00);                   \
    DST[0][1] = *reinterpret_cast<const short8*>(pB01);                   \
    DST[1][0] = *reinterpret_cast<const short8*>(pB10);                   \
    DST[1][1] = *reinterpret_cast<const short8*>(pB11);                   \
    pB00 += 32; pB01 += 32; pB10 += 32; pB11 += 32; } while (0)

#define FENCE() asm volatile("" ::: "memory")
#define VM6()  do { FENCE(); __builtin_amdgcn_s_waitcnt(0x0F76); FENCE(); } while (0)
#define VM0()  do { FENCE(); __builtin_amdgcn_s_waitcnt(0x0F70); FENCE(); } while (0)
#define BAR()  do { FENCE(); __builtin_amdgcn_s_barrier(); FENCE(); } while (0)

// LDS (dynamic, 64KB): 4 slots x A[256][32] bf16 (16KB/slot).
__global__ __launch_bounds__(512, 2) void gemm8_kernel(
        const unsigned short* __restrict__ A,   // M x K (bf16 bits)
        const unsigned short* __restrict__ B,   // N x K (bf16 bits)
        const float* __restrict__ bias,         // N
        float* __restrict__ C,                  // M x N
        int M, int N, int K) {
    extern __shared__ unsigned short smem[];
    const int t = threadIdx.x;
    const int lane = t & 63;
    const int w = t >> 6;
    const int wrow = w >> 2;   // 0..1
    const int wcol = w & 3;    // 0..3
    const int fr  = lane & 15;
    const int kb  = lane >> 4; // 0..3

    // T1: bijective XCD swizzle (nwg = 512, % 8 == 0)
    const int nwg = gridDim.x;
    const int bid = blockIdx.x;
    const int cpx = nwg >> 3;
    const int swz = (bid & 7) * cpx + (bid >> 3);
    const int ntN = N >> 8;
    const int bm = (swz / ntN) << 8;
    const int bn = (swz % ntN) << 8;

    // A stage pointers (r15-validated), +32 els/tile.
    const int r0  = t >> 2;
    const int cbo = ((t & 3) ^ ((t >> 3) & 3)) * 8;
    const unsigned short* pA0 = A + (size_t)(bm +       r0) * K + cbo;
    const unsigned short* pA1 = A + (size_t)(bm + 128 + r0) * K + cbo;

    // B fragment pointers (validated r26): col = bn + qn*128 + wcol*32 + nf*16 + fr.
    const unsigned short* pB00 = B + (size_t)(bn +       wcol * 32 +      fr) * K + kb * 8;
    const unsigned short* pB01 = B + (size_t)(bn +       wcol * 32 + 16 + fr) * K + kb * 8;
    const unsigned short* pB10 = B + (size_t)(bn + 128 + wcol * 32 +      fr) * K + kb * 8;
    const unsigned short* pB11 = B + (size_t)(bn + 128 + wcol * 32 + 16 + fr) * K + kb * 8;

    // Swizzled A read base (bytes, slot 0).
    const int xk = ((kb ^ ((fr >> 1) & 3)) << 4);
    const char* sbase = (const char*)smem;
    const char* aRow = sbase + (wrow * 64 + fr) * 64 + xk;   // +sb +mf*1024 (+8192 A1)

    // Prologue: stage A(0)->s0, A(1)->s1; load B(0)->rb0, B(1)->rb1; drain.
    STAGE_A(smem);
    STAGE_A(smem + 8192);
    short8 rb0[2][2], rb1[2][2], rb2[2][2];
    LOAD_B(rb0);
    LOAD_B(rb1);
    VM0();

    floatx4 acc[2][2][4][2] = {};   // [qm][qn][mf][nf]
    const int NT = K >> 5;          // 128

    // Body(T): BAR; read A-frags(T) slot T&3; issue B4(T+2)->W, A2(T+2)->
    // slot (T+2)&3 (= (T-2)&3, WAR safe); 32 MFMA on A(T) x U=B(T);
    // gate: T+2<NT: VM6 (queue {B,A}(T+1),{B,A}(T+2)=12 -> retires T+1);
    // T+1==NT-1: VM0; last: none.
    auto body = [&](int T, short8 (&U)[2][2], short8 (&W)[2][2])
            __attribute__((always_inline)) {
        BAR();
        const int sb = (T & 3) << 14;

        short8 af0[4], af1[4];
        #pragma unroll
        for (int mf = 0; mf < 4; ++mf) {
            af0[mf] = *reinterpret_cast<const short8*>(aRow + sb +        mf * 1024);
            af1[mf] = *reinterpret_cast<const short8*>(aRow + sb + 8192 + mf * 1024);
        }

        if (T + 2 < NT) {
            LOAD_B(W);
            STAGE_A(smem + ((T + 2) & 3) * 8192);
        }

        #pragma unroll
        for (int mf = 0; mf < 4; ++mf)
          #pragma unroll
          for (int nf = 0; nf < 2; ++nf) {
            acc[0][0][mf][nf] = __builtin_amdgcn_mfma_f32_16x16x32_bf16(
                af0[mf], U[0][nf], acc[0][0][mf][nf], 0, 0, 0);
            acc[0][1][mf][nf] = __builtin_amdgcn_mfma_f32_16x16x32_bf16(
                af0[mf], U[1][nf], acc[0][1][mf][nf], 0, 0, 0);
            acc[1][1][mf][nf] = __builtin_amdgcn_mfma_f32_16x16x32_bf16(
                af1[mf], U[1][nf], acc[1][1][mf][nf], 0, 0, 0);
            acc[1][0][mf][nf] = __builtin_amdgcn_mfma_f32_16x16x32_bf16(
                af1[mf], U[0][nf], acc[1][0][mf][nf], 0, 0, 0);
          }

        if (T + 2 < NT)      { VM6(); }
        else if (T + 1 < NT) { VM0(); }
    };

    // NT = 128 = 3*42 + 2: main loop covers T=0..125, tail 126,127.
    // Rotation: tile T consumes rb[T%3], writes rb[(T+2)%3].
    int T = 0;
    for (; T + 2 < NT; T += 3) {
        body(T,     rb0, rb2);
        body(T + 1, rb1, rb0);
        body(T + 2, rb2, rb1);
    }
    if (T     < NT) body(T,     rb0, rb2);   // T=126: consumes rb[126%3=0]
    if (T + 1 < NT) body(T + 1, rb1, rb0);   // T=127: consumes rb[127%3=1]

    // Epilogue: C/D layout col=lane&15, row=(lane>>4)*4+reg (validated)
    #pragma unroll
    for (int qm = 0; qm < 2; ++qm)
      #pragma unroll
      for (int qn = 0; qn < 2; ++qn)
        #pragma unroll
        for (int nf = 0; nf < 2; ++nf) {
            const int gcol = bn + qn * 128 + wcol * 32 + nf * 16 + (lane & 15);
            const float bq = qfix(bias[gcol]);
            #pragma unroll
            for (int mf = 0; mf < 4; ++mf) {
                const int grow = bm + qm * 128 + wrow * 64 + mf * 16 + ((lane >> 4) << 2);
                float* p = C + (size_t)grow * N + gcol;
                #pragma unroll
                for (int r = 0; r < 4; ++r)
                    p[(size_t)r * N] = acc[qm][qn][mf][nf][r] + bq;
            }
        }
}

extern "C" void kernel_launch(void* const* d_in, const int* in_sizes, int n_in,
                              void* d_out, int out_size, void* d_ws, size_t ws_size,
                              hipStream_t stream) {
    const float* x     = (const float*)d_in[0];
    const float* shift = (const float*)d_in[1];
    const float* sign  = (const float*)d_in[2];
    const float* bias  = (const float*)d_in[3];
    float* out = (float*)d_out;

    const int N = in_sizes[3];            // 4096
    const int K = in_sizes[1] / N;        // 4096
    const int M = in_sizes[0] / K;        // 8192

    unsigned short* xq = (unsigned short*)d_ws;
    unsigned short* v  = xq + (size_t)M * K;

    quantize_x_kernel<<<2048, 256, 0, stream>>>(x, xq, M * K / 4);
    make_v_kernel<<<2048, 256, 0, stream>>>(shift, sign, v, N * K / 4);

    (void)hipFuncSetAttribute(reinterpret_cast<const void*>(gemm8_kernel),
                              hipFuncAttributeMaxDynamicSharedMemorySize, 65536);
    const int nblk = (M / 256) * (N / 256);   // 512
    gemm8_kernel<<<nblk, 512, 65536, stream>>>(xq, v, bias, out, M, N, K);
}